// Round 9
// baseline (644.466 us; speedup 1.0000x reference)
//
#include <hip/hip_runtime.h>

typedef float f32x4 __attribute__((ext_vector_type(4)));
typedef __bf16 bf16x8 __attribute__((ext_vector_type(8)));

#define IMH 256
#define IMW 256
#define NCH 128
#define NHEAD 4
#define NWIN 1024
#define DWIN 2048
#define HW (IMH*IMW)

__device__ __forceinline__ unsigned short bf16u(float f) {
  __bf16 h = (__bf16)f;
  return __builtin_bit_cast(unsigned short, h);
}
__device__ __forceinline__ unsigned int pk2(float a, float b) {
  return (unsigned int)bf16u(a) | ((unsigned int)bf16u(b) << 16);
}
__device__ __forceinline__ f32x4 fzero() { f32x4 z = {0.f, 0.f, 0.f, 0.f}; return z; }

// wo [o][c][3][3] -> wot [kk][cgrp][o][c32]  (A-frag loads are 1KB contiguous)
__global__ void k_prep_wo(const float* __restrict__ wo, __bf16* __restrict__ wot) {
  int i = blockIdx.x * 256 + threadIdx.x;
  if (i < 9*16384) {
    int c32 = i & 31;
    int o   = (i >> 5) & 127;
    int cg  = (i >> 12) & 3;
    int kk  = i >> 14;
    wot[i] = (__bf16)wo[(o*128 + cg*32 + c32)*9 + kk];
  }
}

// ---------------- x transpose: x[b][c][h][w] f32 -> xt16[b][h][w][c] bf16 -------------
__global__ __launch_bounds__(256)
void k_xpose(const float* __restrict__ x, unsigned short* __restrict__ xt16) {
  __shared__ __align__(16) float xf[64*68];
  const int bid = blockIdx.x;
  const int wq4 = bid & 3, h = (bid >> 2) & 255, ch = (bid >> 10) & 1, b = bid >> 11;
  const int w0 = wq4*64, c0 = ch*64;
  const int t = threadIdx.x;
  {
    const int wquad = t & 15, ci0 = t >> 4;   // ci0 0..15
    #pragma unroll
    for (int p = 0; p < 4; ++p) {
      int ci = ci0 + p*16;
      const float* src = x + (size_t)(b*NCH + c0 + ci)*HW + h*256 + w0 + wquad*4;
      float4 v = *(const float4*)src;
      *(float4*)&xf[ci*68 + wquad*4] = v;
    }
  }
  __syncthreads();
  {
    const int wl = t >> 2, cq = t & 3;        // wl 0..63, cq: 16-c chunk
    unsigned short vv[16];
    #pragma unroll
    for (int k = 0; k < 16; ++k) {
      int kp = (k + cq*4) & 15;               // rotate to break 4-way bank conflict
      vv[kp] = bf16u(xf[(cq*16 + kp)*68 + wl]);
    }
    unsigned short* dp = xt16 + ((size_t)(b*65536) + (size_t)h*256 + w0 + wl)*128 + c0 + cq*16;
    uint4 o0, o1;
    o0.x = (unsigned)vv[0] | ((unsigned)vv[1]<<16);  o0.y = (unsigned)vv[2] | ((unsigned)vv[3]<<16);
    o0.z = (unsigned)vv[4] | ((unsigned)vv[5]<<16);  o0.w = (unsigned)vv[6] | ((unsigned)vv[7]<<16);
    o1.x = (unsigned)vv[8] | ((unsigned)vv[9]<<16);  o1.y = (unsigned)vv[10]| ((unsigned)vv[11]<<16);
    o1.z = (unsigned)vv[12]| ((unsigned)vv[13]<<16); o1.w = (unsigned)vv[14]| ((unsigned)vv[15]<<16);
    ((uint4*)dp)[0] = o0;
    ((uint4*)dp)[1] = o1;
  }
}

// ---------------- Q/K projection GEMM (rp aliases staging -> 34.8KB LDS) -------------
__global__ __launch_bounds__(512)
void k_qk(const unsigned short* __restrict__ xt16,
          const float* __restrict__ wq, const float* __restrict__ wk,
          const float* __restrict__ bqp, const float* __restrict__ bkp,
          __bf16* __restrict__ qw, __bf16* __restrict__ kw) {
  __shared__ __align__(16) char lds[34816];
  unsigned short* Asm = (unsigned short*)lds;             // 128 x 80B
  unsigned short* Bq  = (unsigned short*)(lds + 10240);   // 128 x 80B
  unsigned short* Bk  = (unsigned short*)(lds + 20480);   // 128 x 80B
  unsigned short* rp  = (unsigned short*)lds;             // alias: 128 x 272B (post-GEMM)
  const int bidx = blockIdx.x;            // 2048
  const int b = bidx >> 9, mt = bidx & 511;
  const int n0 = mt*2, oy = n0 >> 5;
  const int t = threadIdx.x, lane = t & 63, wid = t >> 6;
  const int wm = wid >> 2, wn = wid & 3;  // wm: m 64-half, wn: o 32-quarter
  const int l15 = lane & 15, l4 = lane >> 4;
  const int ra = t >> 2, ca = t & 3;
  const int nA = n0 + (ra >> 6), ppA = ra & 63;
  const unsigned short* Abase = xt16 +
      ((size_t)(b*65536) + (size_t)(oy*8 + (ppA>>3))*256 + (nA&31)*8 + (ppA&7))*128 + ca*8;
  const float* wqb = wq + ra*128 + ca*8;
  const float* wkb = wk + ra*128 + ca*8;

  f32x4 aq[2][4], ak[2][4];
  #pragma unroll
  for (int i = 0; i < 2; ++i)
    #pragma unroll
    for (int j = 0; j < 4; ++j) { aq[i][j] = fzero(); ak[i][j] = fzero(); }

  #pragma unroll
  for (int kt = 0; kt < 4; ++kt) {
    __syncthreads();
    *(uint4*)((char*)Asm + ra*80 + ca*16) = *(const uint4*)(Abase + kt*32);
    {
      float4 f0 = *(const float4*)(wqb + kt*32);
      float4 f1 = *(const float4*)(wqb + kt*32 + 4);
      uint4 bv; bv.x = pk2(f0.x,f0.y); bv.y = pk2(f0.z,f0.w);
      bv.z = pk2(f1.x,f1.y); bv.w = pk2(f1.z,f1.w);
      *(uint4*)((char*)Bq + ra*80 + ca*16) = bv;
    }
    {
      float4 f0 = *(const float4*)(wkb + kt*32);
      float4 f1 = *(const float4*)(wkb + kt*32 + 4);
      uint4 bv; bv.x = pk2(f0.x,f0.y); bv.y = pk2(f0.z,f0.w);
      bv.z = pk2(f1.x,f1.y); bv.w = pk2(f1.z,f1.w);
      *(uint4*)((char*)Bk + ra*80 + ca*16) = bv;
    }
    __syncthreads();
    bf16x8 awq[2], awk[2], xm[4];
    #pragma unroll
    for (int i = 0; i < 2; ++i) {
      int o = wn*32 + i*16 + l15;
      awq[i] = *(const bf16x8*)((const char*)Bq + o*80 + l4*16);
      awk[i] = *(const bf16x8*)((const char*)Bk + o*80 + l4*16);
    }
    #pragma unroll
    for (int j = 0; j < 4; ++j) {
      int m = wm*64 + j*16 + l15;
      xm[j] = *(const bf16x8*)((const char*)Asm + m*80 + l4*16);
    }
    #pragma unroll
    for (int i = 0; i < 2; ++i)
      #pragma unroll
      for (int j = 0; j < 4; ++j) {
        aq[i][j] = __builtin_amdgcn_mfma_f32_16x16x32_bf16(awq[i], xm[j], aq[i][j], 0, 0, 0);
        ak[i][j] = __builtin_amdgcn_mfma_f32_16x16x32_bf16(awk[i], xm[j], ak[i][j], 0, 0, 0);
      }
  }
  __syncthreads();
  const int ploc = t & 127, nh = t >> 7;
  // ---- mat Q ----
  #pragma unroll
  for (int i = 0; i < 2; ++i) {
    int o0 = wn*32 + i*16 + l4*4;
    float4 bi = *(const float4*)(bqp + o0);
    #pragma unroll
    for (int j = 0; j < 4; ++j) {
      int m = wm*64 + j*16 + l15;
      uint2 pw;
      pw.x = pk2(aq[i][j][0] + bi.x, aq[i][j][1] + bi.y);
      pw.y = pk2(aq[i][j][2] + bi.z, aq[i][j][3] + bi.w);
      *(uint2*)((char*)rp + m*272 + o0*2) = pw;
    }
  }
  __syncthreads();
  {
    unsigned short* dp = (unsigned short*)qw +
        (size_t)(b*NHEAD + nh)*NWIN*DWIN + (size_t)(mt*128 + ploc)*32;
    #pragma unroll
    for (int q = 0; q < 4; ++q)
      ((uint4*)dp)[q] = *(const uint4*)((const char*)rp + ploc*272 + (nh*32 + q*8)*2);
  }
  __syncthreads();
  // ---- mat K ----
  #pragma unroll
  for (int i = 0; i < 2; ++i) {
    int o0 = wn*32 + i*16 + l4*4;
    float4 bi = *(const float4*)(bkp + o0);
    #pragma unroll
    for (int j = 0; j < 4; ++j) {
      int m = wm*64 + j*16 + l15;
      uint2 pw;
      pw.x = pk2(ak[i][j][0] + bi.x, ak[i][j][1] + bi.y);
      pw.y = pk2(ak[i][j][2] + bi.z, ak[i][j][3] + bi.w);
      *(uint2*)((char*)rp + m*272 + o0*2) = pw;
    }
  }
  __syncthreads();
  {
    unsigned short* dp = (unsigned short*)kw +
        (size_t)(b*NHEAD + nh)*NWIN*DWIN + (size_t)(mt*128 + ploc)*32;
    #pragma unroll
    for (int q = 0; q < 4; ++q)
      ((uint4*)dp)[q] = *(const uint4*)((const char*)rp + ploc*272 + (nh*32 + q*8)*2);
  }
}

// ---------------- V projection GEMM ----------------
__global__ __launch_bounds__(512)
void k_v(const unsigned short* __restrict__ xt16, const float* __restrict__ wv,
         const float* __restrict__ bvp, __bf16* __restrict__ vt) {
  __shared__ __align__(16) char lds[44544];
  unsigned short* Asm = (unsigned short*)lds;            // 512 x 80B = 40960
  unsigned short* Bsm = (unsigned short*)(lds + 40960);  // 32 x 80B
  unsigned short* rp  = (unsigned short*)lds;            // alias: 32 x 1040B (after barrier)
  const int bx = blockIdx.x;             // 512 = 4b x 128 mt
  const int b = bx >> 7, mt = bx & 127;
  const int nh = blockIdx.y;
  const int oy = mt >> 2, ox0 = (mt & 3)*8;
  const int t = threadIdx.x, lane = t & 63, wv8 = t >> 6;
  const int l15 = lane & 15, l4 = lane >> 4;
  const unsigned short* Ab[4];
  #pragma unroll
  for (int p = 0; p < 4; ++p) {
    int id = t + p*512;
    int ra = id >> 2, cc = id & 3;
    int oxl = ra >> 6, pp = ra & 63;
    Ab[p] = xt16 + ((size_t)(b*65536) + (size_t)(oy*8 + (pp>>3))*256 + (ox0+oxl)*8 + (pp&7))*128 + cc*8;
  }
  const float* wvb = wv + (nh*32 + (t>>2))*128 + (t&3)*8;

  f32x4 acc[4][2];
  #pragma unroll
  for (int j = 0; j < 4; ++j)
    #pragma unroll
    for (int i = 0; i < 2; ++i) acc[j][i] = fzero();

  #pragma unroll
  for (int kt = 0; kt < 4; ++kt) {
    __syncthreads();
    #pragma unroll
    for (int p = 0; p < 4; ++p) {
      int id = t + p*512;
      *(uint4*)((char*)Asm + (id>>2)*80 + (id&3)*16) = *(const uint4*)(Ab[p] + kt*32);
    }
    if (t < 128) {
      float4 f0 = *(const float4*)(wvb + kt*32);
      float4 f1 = *(const float4*)(wvb + kt*32 + 4);
      uint4 bv; bv.x = pk2(f0.x,f0.y); bv.y = pk2(f0.z,f0.w);
      bv.z = pk2(f1.x,f1.y); bv.w = pk2(f1.z,f1.w);
      *(uint4*)((char*)Bsm + (t>>2)*80 + (t&3)*16) = bv;
    }
    __syncthreads();
    bf16x8 am[4], bw[2];
    #pragma unroll
    for (int j = 0; j < 4; ++j) {
      int m = wv8*64 + j*16 + l15;
      am[j] = *(const bf16x8*)((const char*)Asm + m*80 + l4*16);
    }
    #pragma unroll
    for (int i = 0; i < 2; ++i) {
      int o = i*16 + l15;
      bw[i] = *(const bf16x8*)((const char*)Bsm + o*80 + l4*16);
    }
    #pragma unroll
    for (int j = 0; j < 4; ++j)
      #pragma unroll
      for (int i = 0; i < 2; ++i)
        acc[j][i] = __builtin_amdgcn_mfma_f32_16x16x32_bf16(am[j], bw[i], acc[j][i], 0, 0, 0);
  }
  __syncthreads();           // all Asm/Bsm reads done; rp aliases Asm
  #pragma unroll
  for (int i = 0; i < 2; ++i) {
    int o = i*16 + l15;
    float bi = bvp[nh*32 + o];
    #pragma unroll
    for (int j = 0; j < 4; ++j) {
      int m0 = wv8*64 + j*16 + l4*4;
      uint2 pw;
      pw.x = pk2(acc[j][i][0] + bi, acc[j][i][1] + bi);
      pw.y = pk2(acc[j][i][2] + bi, acc[j][i][3] + bi);
      *(uint2*)((char*)rp + o*1040 + m0*2) = pw;
    }
  }
  __syncthreads();
  #pragma unroll
  for (int it = 0; it < 4; ++it) {
    int id = t + it*512;
    int o = id & 31, pp = id >> 5;   // pp 0..63
    unsigned short vv[8];
    #pragma unroll
    for (int oxl = 0; oxl < 8; ++oxl)
      vv[oxl] = *(const unsigned short*)((const char*)rp + o*1040 + (oxl*64 + pp)*2);
    uint4 val;
    val.x = (unsigned)vv[0] | ((unsigned)vv[1]<<16);
    val.y = (unsigned)vv[2] | ((unsigned)vv[3]<<16);
    val.z = (unsigned)vv[4] | ((unsigned)vv[5]<<16);
    val.w = (unsigned)vv[6] | ((unsigned)vv[7]<<16);
    unsigned short* dp = (unsigned short*)vt +
        ((size_t)((b*NHEAD + nh)*DWIN) + pp*32 + o)*NWIN + mt*8;
    *(uint4*)dp = val;
  }
}

// ---------------- shared 128x128 B^T GEMM tile (reg-staged, 2-barrier) ----------------
__device__ __forceinline__ void gemm_tile(const __bf16* __restrict__ A,
                                          const __bf16* __restrict__ B,
                                          const int lda, const int ldb, const int NT,
                                          unsigned short* Asm, unsigned short* Bsm,
                                          f32x4 (&acc)[4][4]) {
  const int t = threadIdx.x;
  const int lane = t & 63, wid = t >> 6;
  const int wm = wid >> 1, wn = wid & 1;
  const int l15 = lane & 15, l4 = lane >> 4;
  const int u0 = t, u1 = t + 256;
  const int ra0 = u0 >> 2, ca0 = u0 & 3;
  const int ra1 = u1 >> 2, ca1 = u1 & 3;
  uint4 ar0 = *(const uint4*)(A + ra0*lda + ca0*8);
  uint4 ar1 = *(const uint4*)(A + ra1*lda + ca1*8);
  uint4 br0 = *(const uint4*)(B + ra0*ldb + ca0*8);
  uint4 br1 = *(const uint4*)(B + ra1*ldb + ca1*8);
  for (int kt = 0; kt < NT; ++kt) {
    __syncthreads();
    *(uint4*)((char*)Asm + ra0*80 + ca0*16) = ar0;
    *(uint4*)((char*)Asm + ra1*80 + ca1*16) = ar1;
    *(uint4*)((char*)Bsm + ra0*80 + ca0*16) = br0;
    *(uint4*)((char*)Bsm + ra1*80 + ca1*16) = br1;
    __syncthreads();
    if (kt + 1 < NT) {
      int k0 = (kt+1)*32;
      ar0 = *(const uint4*)(A + ra0*lda + k0 + ca0*8);
      ar1 = *(const uint4*)(A + ra1*lda + k0 + ca1*8);
      br0 = *(const uint4*)(B + ra0*ldb + k0 + ca0*8);
      br1 = *(const uint4*)(B + ra1*ldb + k0 + ca1*8);
    }
    bf16x8 a[4], bb[4];
    #pragma unroll
    for (int i = 0; i < 4; ++i)
      a[i] = *(const bf16x8*)((const char*)Asm + (wm*64 + i*16 + l15)*80 + l4*16);
    #pragma unroll
    for (int j = 0; j < 4; ++j)
      bb[j] = *(const bf16x8*)((const char*)Bsm + (wn*64 + j*16 + l15)*80 + l4*16);
    #pragma unroll
    for (int i = 0; i < 4; ++i)
      #pragma unroll
      for (int j = 0; j < 4; ++j)
        acc[i][j] = __builtin_amdgcn_mfma_f32_16x16x32_bf16(a[i], bb[j], acc[i][j], 0, 0, 0);
  }
}

// ---------------- scores = qw . kw^T / sqrt(d) ----------------
__global__ __launch_bounds__(256)
void k_scores(const __bf16* __restrict__ qw, const __bf16* __restrict__ kw,
              float* __restrict__ S) {
  __shared__ __align__(16) unsigned short Asm[5120], Bsm[5120];
  const int bnh = blockIdx.y;
  const int mt = blockIdx.x >> 3, nt = blockIdx.x & 7;
  const __bf16* A = qw + (size_t)bnh*NWIN*DWIN + (size_t)mt*128*DWIN;
  const __bf16* B = kw + (size_t)bnh*NWIN*DWIN + (size_t)nt*128*DWIN;
  f32x4 acc[4][4];
  #pragma unroll
  for (int i = 0; i < 4; ++i)
    #pragma unroll
    for (int j = 0; j < 4; ++j) acc[i][j] = fzero();
  gemm_tile(A, B, DWIN, DWIN, 64, Asm, Bsm, acc);
  const float scale = 0.022097086912079608f;  // 1/sqrt(2048)
  const int t = threadIdx.x, lane = t & 63, wid = t >> 6;
  const int wm = wid >> 1, wn = wid & 1, l15 = lane & 15, l4 = lane >> 4;
  float* Sb = S + (size_t)bnh*NWIN*NWIN + (size_t)(mt*128)*NWIN + nt*128;
  #pragma unroll
  for (int i = 0; i < 4; ++i)
    #pragma unroll
    for (int r = 0; r < 4; ++r) {
      int row = wm*64 + i*16 + l4*4 + r;
      #pragma unroll
      for (int j = 0; j < 4; ++j) {
        int col = wn*64 + j*16 + l15;
        Sb[(size_t)row*NWIN + col] = acc[i][j][r] * scale;
      }
    }
}

// ---------------- row softmax: S f32 -> P bf16 ----------------
__global__ __launch_bounds__(256)
void k_softmax(const float* __restrict__ S, __bf16* __restrict__ P) {
  __shared__ float red[8];
  const int row = blockIdx.x;
  const int t = threadIdx.x;
  const float4 v = ((const float4*)(S + (size_t)row*NWIN))[t];
  float m = fmaxf(fmaxf(v.x, v.y), fmaxf(v.z, v.w));
  for (int off = 1; off < 64; off <<= 1) m = fmaxf(m, __shfl_xor(m, off));
  const int wid = t >> 6, lane = t & 63;
  if (lane == 0) red[wid] = m;
  __syncthreads();
  m = fmaxf(fmaxf(red[0], red[1]), fmaxf(red[2], red[3]));
  float e0 = __expf(v.x - m), e1 = __expf(v.y - m), e2 = __expf(v.z - m), e3 = __expf(v.w - m);
  float s = e0 + e1 + e2 + e3;
  for (int off = 1; off < 64; off <<= 1) s += __shfl_xor(s, off);
  if (lane == 0) red[4 + wid] = s;
  __syncthreads();
  s = red[4] + red[5] + red[6] + red[7];
  float inv = 1.0f / s;
  ushort4 o;
  o.x = bf16u(e0*inv); o.y = bf16u(e1*inv); o.z = bf16u(e2*inv); o.w = bf16u(e3*inv);
  ((ushort4*)((unsigned short*)P + (size_t)row*NWIN))[t] = o;
}

// ---------------- y = P . V  (B = vt[d''][m]) -> y3[b][cgrp][h][w][c32] ----------------
__global__ __launch_bounds__(256)
void k_pv(const __bf16* __restrict__ P, const __bf16* __restrict__ vt,
          __bf16* __restrict__ y3) {
  __shared__ __align__(16) unsigned short Asm[5120], Bsm[5120];
  const int bnh = blockIdx.y;
  const int b = bnh >> 2, nh = bnh & 3;
  const int mt = blockIdx.x >> 4, nt = blockIdx.x & 15;
  const __bf16* A = P  + (size_t)bnh*NWIN*NWIN + (size_t)mt*128*NWIN;
  const __bf16* B = vt + (size_t)bnh*DWIN*NWIN + (size_t)nt*128*NWIN;
  f32x4 acc[4][4];
  #pragma unroll
  for (int i = 0; i < 4; ++i)
    #pragma unroll
    for (int j = 0; j < 4; ++j) acc[i][j] = fzero();
  gemm_tile(A, B, NWIN, NWIN, 32, Asm, Bsm, acc);
  const int t = threadIdx.x, lane = t & 63, wid = t >> 6;
  const int wm = wid >> 1, wn = wid & 1, l15 = lane & 15, l4 = lane >> 4;
  unsigned short* yu = (unsigned short*)y3;
  const size_t cbase = (size_t)(b*NHEAD + nh)*65536*32;
  #pragma unroll
  for (int i = 0; i < 4; ++i)
    #pragma unroll
    for (int r = 0; r < 4; ++r) {
      int n = mt*128 + wm*64 + i*16 + l4*4 + r;
      int oyy = n >> 5, oxx = n & 31;
      #pragma unroll
      for (int j = 0; j < 4; ++j) {
        int pp = nt*4 + wn*2 + (j >> 1);
        int dk = (j & 1)*16 + l15;
        int hh = oyy*8 + (pp >> 3), ww = oxx*8 + (pp & 7);
        yu[cbase + ((size_t)hh*256 + ww)*32 + dk] = bf16u(acc[i][j][r]);
      }
    }
}

// ---------------- 3x3 reflect conv + bias + LeakyReLU ----------------
// Quarter-row blocks (64 px): LDS 15.8KB -> 8 blocks/CU, latency overlaps.
__global__ __launch_bounds__(256)
void k_conv(const __bf16* __restrict__ y3, const __bf16* __restrict__ wot,
            const float* __restrict__ bo, float* __restrict__ out) {
  __shared__ __align__(16) unsigned short ylds[7920];   // 198 slots * 80B
  const int bid = blockIdx.x;
  const int quarter = bid & 3, h = (bid >> 2) & 255, b = bid >> 10;
  const int w0 = quarter * 64;
  const int t = threadIdx.x;
  const int hm1 = (h == 0) ? 1 : h - 1;
  const int hp1 = (h == 255) ? 254 : h + 1;
  const int lane = t & 63, wid = t >> 6;
  const int wm = wid >> 1, wn = wid & 1, l15 = lane & 15, l4 = lane >> 4;
  f32x4 acc[4][2];
  #pragma unroll
  for (int i = 0; i < 4; ++i)
    #pragma unroll
    for (int j = 0; j < 2; ++j) acc[i][j] = fzero();
  const unsigned short* yu = (const unsigned short*)y3;
  for (int cc = 0; cc < 4; ++cc) {
    const size_t cbase = (size_t)(b*NHEAD + cc)*65536*32;
    __syncthreads();
    // 3 rows x 66 wl x 4 segs = 792 uint4: 3 full iterations + 24 tail
    #pragma unroll
    for (int it = 0; it < 3; ++it) {
      int u = it*256 + t;
      int seg = u & 3, q = u >> 2;
      int rowr = (q >= 132) ? 2 : ((q >= 66) ? 1 : 0);
      int wl = q - rowr*66;
      int hh = (rowr == 0) ? hm1 : ((rowr == 1) ? h : hp1);
      int gw = w0 - 1 + wl;
      gw = (gw < 0) ? 1 : ((gw > 255) ? 254 : gw);
      uint4 val = *(const uint4*)(yu + cbase + ((size_t)hh*256 + gw)*32 + seg*8);
      *(uint4*)((char*)ylds + (rowr*66 + wl)*80 + seg*16) = val;
    }
    if (t < 24) {
      int u = 768 + t;
      int seg = u & 3, q = u >> 2;        // q 192..197 -> rowr 2, wl 60..65
      int wl = q - 132;
      int gw = w0 - 1 + wl;
      gw = (gw > 255) ? 254 : gw;
      uint4 val = *(const uint4*)(yu + cbase + ((size_t)hp1*256 + gw)*32 + seg*8);
      *(uint4*)((char*)ylds + (132 + wl)*80 + seg*16) = val;
    }
    __syncthreads();
    #pragma unroll
    for (int kk = 0; kk < 9; ++kk) {
      const int ky = kk / 3, kx = kk % 3;
      bf16x8 a[4], bb[2];
      #pragma unroll
      for (int i = 0; i < 4; ++i) {
        int o = wm*64 + i*16 + l15;
        a[i] = *(const bf16x8*)(wot + ((size_t)(kk*4 + cc)*128 + o)*32 + l4*8);
      }
      #pragma unroll
      for (int j = 0; j < 2; ++j) {
        int px = wn*32 + j*16 + l15;
        int R = ky*66 + px + kx;
        bb[j] = *(const bf16x8*)((const char*)ylds + R*80 + l4*16);
      }
      #pragma unroll
      for (int i = 0; i < 4; ++i)
        #pragma unroll
        for (int j = 0; j < 2; ++j)
          acc[i][j] = __builtin_amdgcn_mfma_f32_16x16x32_bf16(a[i], bb[j], acc[i][j], 0, 0, 0);
    }
  }
  #pragma unroll
  for (int i = 0; i < 4; ++i)
    #pragma unroll
    for (int r2 = 0; r2 < 4; ++r2) {
      int o = wm*64 + i*16 + l4*4 + r2;
      float bi = bo[o];
      #pragma unroll
      for (int j = 0; j < 2; ++j) {
        int px = wn*32 + j*16 + l15;
        float v = acc[i][j][r2] + bi;
        v = (v > 0.f) ? v : 0.2f * v;
        out[(size_t)((b*NCH + o)*IMH + h)*IMW + w0 + px] = v;
      }
    }
}

// ---------------- launcher ----------------
extern "C" void kernel_launch(void* const* d_in, const int* in_sizes, int n_in,
                              void* d_out, int out_size, void* d_ws, size_t ws_size,
                              hipStream_t stream) {
  (void)in_sizes; (void)n_in; (void)out_size; (void)ws_size;
  const float* x  = (const float*)d_in[0];
  // d_in[1] = m : mask is a no-op in the reference
  const float* wq = (const float*)d_in[2];
  const float* bq = (const float*)d_in[3];
  const float* wk = (const float*)d_in[4];
  const float* bk = (const float*)d_in[5];
  const float* wv = (const float*)d_in[6];
  const float* bv = (const float*)d_in[7];
  const float* wo = (const float*)d_in[8];
  const float* bo = (const float*)d_in[9];
  float* out = (float*)d_out;
  char* ws = (char*)d_ws;
  // region A [0,64MB): qw -> P ; B [64,128MB): kw -> wot ; C [128,192MB): vt
  // region D [192,256MB): xt16 -> S f32 -> y3 bf16
  __bf16* qw  = (__bf16*)(ws + 0);
  __bf16* kw  = (__bf16*)(ws + 67108864);
  __bf16* vt  = (__bf16*)(ws + 134217728);
  unsigned short* xt16 = (unsigned short*)(ws + 201326592);
  float*  S   = (float*)(ws + 201326592);
  __bf16* P   = (__bf16*)(ws + 0);
  __bf16* y3  = (__bf16*)(ws + 201326592);
  __bf16* wot = (__bf16*)(ws + 67108864);

  k_xpose<<<8192, 256, 0, stream>>>(x, xt16);
  k_qk<<<2048, 512, 0, stream>>>(xt16, wq, wk, bq, bk, qw, kw);
  k_v<<<dim3(512, 4), 512, 0, stream>>>(xt16, wv, bv, vt);
  k_scores<<<dim3(64, 16), 256, 0, stream>>>(qw, kw, S);
  k_prep_wo<<<576, 256, 0, stream>>>(wo, wot);
  k_softmax<<<16384, 256, 0, stream>>>(S, P);
  k_pv<<<dim3(128, 16), 256, 0, stream>>>(P, vt, y3);
  k_conv<<<4096, 256, 0, stream>>>(y3, wot, bo, out);
}

// Round 10
// 581.162 us; speedup vs baseline: 1.1089x; 1.1089x over previous
//
#include <hip/hip_runtime.h>

typedef float f32x4 __attribute__((ext_vector_type(4)));
typedef __bf16 bf16x8 __attribute__((ext_vector_type(8)));

#define IMH 256
#define IMW 256
#define NCH 128
#define NHEAD 4
#define NWIN 1024
#define DWIN 2048
#define HW (IMH*IMW)

__device__ __forceinline__ unsigned short bf16u(float f) {
  __bf16 h = (__bf16)f;
  return __builtin_bit_cast(unsigned short, h);
}
__device__ __forceinline__ unsigned int pk2(float a, float b) {
  return (unsigned int)bf16u(a) | ((unsigned int)bf16u(b) << 16);
}
__device__ __forceinline__ f32x4 fzero() { f32x4 z = {0.f, 0.f, 0.f, 0.f}; return z; }

// wo [o][c][3][3] -> wot [kk][cgrp][o][c32]  (A-frag loads are 1KB contiguous)
__global__ void k_prep_wo(const float* __restrict__ wo, __bf16* __restrict__ wot) {
  int i = blockIdx.x * 256 + threadIdx.x;
  if (i < 9*16384) {
    int c32 = i & 31;
    int o   = (i >> 5) & 127;
    int cg  = (i >> 12) & 3;
    int kk  = i >> 14;
    wot[i] = (__bf16)wo[(o*128 + cg*32 + c32)*9 + kk];
  }
}

// ---------------- x transpose: x[b][c][h][w] f32 -> xt16[b][h][w][c] bf16 -------------
__global__ __launch_bounds__(256)
void k_xpose(const float* __restrict__ x, unsigned short* __restrict__ xt16) {
  __shared__ __align__(16) float xf[64*68];
  const int bid = blockIdx.x;
  const int wq4 = bid & 3, h = (bid >> 2) & 255, ch = (bid >> 10) & 1, b = bid >> 11;
  const int w0 = wq4*64, c0 = ch*64;
  const int t = threadIdx.x;
  {
    const int wquad = t & 15, ci0 = t >> 4;   // ci0 0..15
    #pragma unroll
    for (int p = 0; p < 4; ++p) {
      int ci = ci0 + p*16;
      const float* src = x + (size_t)(b*NCH + c0 + ci)*HW + h*256 + w0 + wquad*4;
      float4 v = *(const float4*)src;
      *(float4*)&xf[ci*68 + wquad*4] = v;
    }
  }
  __syncthreads();
  {
    const int wl = t >> 2, cq = t & 3;        // wl 0..63, cq: 16-c chunk
    unsigned short vv[16];
    #pragma unroll
    for (int k = 0; k < 16; ++k) {
      int kp = (k + cq*4) & 15;               // rotate to break 4-way bank conflict
      vv[kp] = bf16u(xf[(cq*16 + kp)*68 + wl]);
    }
    unsigned short* dp = xt16 + ((size_t)(b*65536) + (size_t)h*256 + w0 + wl)*128 + c0 + cq*16;
    uint4 o0, o1;
    o0.x = (unsigned)vv[0] | ((unsigned)vv[1]<<16);  o0.y = (unsigned)vv[2] | ((unsigned)vv[3]<<16);
    o0.z = (unsigned)vv[4] | ((unsigned)vv[5]<<16);  o0.w = (unsigned)vv[6] | ((unsigned)vv[7]<<16);
    o1.x = (unsigned)vv[8] | ((unsigned)vv[9]<<16);  o1.y = (unsigned)vv[10]| ((unsigned)vv[11]<<16);
    o1.z = (unsigned)vv[12]| ((unsigned)vv[13]<<16); o1.w = (unsigned)vv[14]| ((unsigned)vv[15]<<16);
    ((uint4*)dp)[0] = o0;
    ((uint4*)dp)[1] = o1;
  }
}

// ---------------- Q/K projection GEMM (rp aliases staging -> 34.8KB LDS) -------------
__global__ __launch_bounds__(512)
void k_qk(const unsigned short* __restrict__ xt16,
          const float* __restrict__ wq, const float* __restrict__ wk,
          const float* __restrict__ bqp, const float* __restrict__ bkp,
          __bf16* __restrict__ qw, __bf16* __restrict__ kw) {
  __shared__ __align__(16) char lds[34816];
  unsigned short* Asm = (unsigned short*)lds;             // 128 x 80B
  unsigned short* Bq  = (unsigned short*)(lds + 10240);   // 128 x 80B
  unsigned short* Bk  = (unsigned short*)(lds + 20480);   // 128 x 80B
  unsigned short* rp  = (unsigned short*)lds;             // alias: 128 x 272B (post-GEMM)
  const int bidx = blockIdx.x;            // 2048
  const int b = bidx >> 9, mt = bidx & 511;
  const int n0 = mt*2, oy = n0 >> 5;
  const int t = threadIdx.x, lane = t & 63, wid = t >> 6;
  const int wm = wid >> 2, wn = wid & 3;  // wm: m 64-half, wn: o 32-quarter
  const int l15 = lane & 15, l4 = lane >> 4;
  const int ra = t >> 2, ca = t & 3;
  const int nA = n0 + (ra >> 6), ppA = ra & 63;
  const unsigned short* Abase = xt16 +
      ((size_t)(b*65536) + (size_t)(oy*8 + (ppA>>3))*256 + (nA&31)*8 + (ppA&7))*128 + ca*8;
  const float* wqb = wq + ra*128 + ca*8;
  const float* wkb = wk + ra*128 + ca*8;

  f32x4 aq[2][4], ak[2][4];
  #pragma unroll
  for (int i = 0; i < 2; ++i)
    #pragma unroll
    for (int j = 0; j < 4; ++j) { aq[i][j] = fzero(); ak[i][j] = fzero(); }

  #pragma unroll
  for (int kt = 0; kt < 4; ++kt) {
    __syncthreads();
    *(uint4*)((char*)Asm + ra*80 + ca*16) = *(const uint4*)(Abase + kt*32);
    {
      float4 f0 = *(const float4*)(wqb + kt*32);
      float4 f1 = *(const float4*)(wqb + kt*32 + 4);
      uint4 bv; bv.x = pk2(f0.x,f0.y); bv.y = pk2(f0.z,f0.w);
      bv.z = pk2(f1.x,f1.y); bv.w = pk2(f1.z,f1.w);
      *(uint4*)((char*)Bq + ra*80 + ca*16) = bv;
    }
    {
      float4 f0 = *(const float4*)(wkb + kt*32);
      float4 f1 = *(const float4*)(wkb + kt*32 + 4);
      uint4 bv; bv.x = pk2(f0.x,f0.y); bv.y = pk2(f0.z,f0.w);
      bv.z = pk2(f1.x,f1.y); bv.w = pk2(f1.z,f1.w);
      *(uint4*)((char*)Bk + ra*80 + ca*16) = bv;
    }
    __syncthreads();
    bf16x8 awq[2], awk[2], xm[4];
    #pragma unroll
    for (int i = 0; i < 2; ++i) {
      int o = wn*32 + i*16 + l15;
      awq[i] = *(const bf16x8*)((const char*)Bq + o*80 + l4*16);
      awk[i] = *(const bf16x8*)((const char*)Bk + o*80 + l4*16);
    }
    #pragma unroll
    for (int j = 0; j < 4; ++j) {
      int m = wm*64 + j*16 + l15;
      xm[j] = *(const bf16x8*)((const char*)Asm + m*80 + l4*16);
    }
    #pragma unroll
    for (int i = 0; i < 2; ++i)
      #pragma unroll
      for (int j = 0; j < 4; ++j) {
        aq[i][j] = __builtin_amdgcn_mfma_f32_16x16x32_bf16(awq[i], xm[j], aq[i][j], 0, 0, 0);
        ak[i][j] = __builtin_amdgcn_mfma_f32_16x16x32_bf16(awk[i], xm[j], ak[i][j], 0, 0, 0);
      }
  }
  __syncthreads();
  const int ploc = t & 127, nh = t >> 7;
  // ---- mat Q ----
  #pragma unroll
  for (int i = 0; i < 2; ++i) {
    int o0 = wn*32 + i*16 + l4*4;
    float4 bi = *(const float4*)(bqp + o0);
    #pragma unroll
    for (int j = 0; j < 4; ++j) {
      int m = wm*64 + j*16 + l15;
      uint2 pw;
      pw.x = pk2(aq[i][j][0] + bi.x, aq[i][j][1] + bi.y);
      pw.y = pk2(aq[i][j][2] + bi.z, aq[i][j][3] + bi.w);
      *(uint2*)((char*)rp + m*272 + o0*2) = pw;
    }
  }
  __syncthreads();
  {
    unsigned short* dp = (unsigned short*)qw +
        (size_t)(b*NHEAD + nh)*NWIN*DWIN + (size_t)(mt*128 + ploc)*32;
    #pragma unroll
    for (int q = 0; q < 4; ++q)
      ((uint4*)dp)[q] = *(const uint4*)((const char*)rp + ploc*272 + (nh*32 + q*8)*2);
  }
  __syncthreads();
  // ---- mat K ----
  #pragma unroll
  for (int i = 0; i < 2; ++i) {
    int o0 = wn*32 + i*16 + l4*4;
    float4 bi = *(const float4*)(bkp + o0);
    #pragma unroll
    for (int j = 0; j < 4; ++j) {
      int m = wm*64 + j*16 + l15;
      uint2 pw;
      pw.x = pk2(ak[i][j][0] + bi.x, ak[i][j][1] + bi.y);
      pw.y = pk2(ak[i][j][2] + bi.z, ak[i][j][3] + bi.w);
      *(uint2*)((char*)rp + m*272 + o0*2) = pw;
    }
  }
  __syncthreads();
  {
    unsigned short* dp = (unsigned short*)kw +
        (size_t)(b*NHEAD + nh)*NWIN*DWIN + (size_t)(mt*128 + ploc)*32;
    #pragma unroll
    for (int q = 0; q < 4; ++q)
      ((uint4*)dp)[q] = *(const uint4*)((const char*)rp + ploc*272 + (nh*32 + q*8)*2);
  }
}

// ---------------- V projection GEMM ----------------
__global__ __launch_bounds__(512)
void k_v(const unsigned short* __restrict__ xt16, const float* __restrict__ wv,
         const float* __restrict__ bvp, __bf16* __restrict__ vt) {
  __shared__ __align__(16) char lds[44544];
  unsigned short* Asm = (unsigned short*)lds;            // 512 x 80B = 40960
  unsigned short* Bsm = (unsigned short*)(lds + 40960);  // 32 x 80B
  unsigned short* rp  = (unsigned short*)lds;            // alias: 32 x 1040B (after barrier)
  const int bx = blockIdx.x;             // 512 = 4b x 128 mt
  const int b = bx >> 7, mt = bx & 127;
  const int nh = blockIdx.y;
  const int oy = mt >> 2, ox0 = (mt & 3)*8;
  const int t = threadIdx.x, lane = t & 63, wv8 = t >> 6;
  const int l15 = lane & 15, l4 = lane >> 4;
  const unsigned short* Ab[4];
  #pragma unroll
  for (int p = 0; p < 4; ++p) {
    int id = t + p*512;
    int ra = id >> 2, cc = id & 3;
    int oxl = ra >> 6, pp = ra & 63;
    Ab[p] = xt16 + ((size_t)(b*65536) + (size_t)(oy*8 + (pp>>3))*256 + (ox0+oxl)*8 + (pp&7))*128 + cc*8;
  }
  const float* wvb = wv + (nh*32 + (t>>2))*128 + (t&3)*8;

  f32x4 acc[4][2];
  #pragma unroll
  for (int j = 0; j < 4; ++j)
    #pragma unroll
    for (int i = 0; i < 2; ++i) acc[j][i] = fzero();

  #pragma unroll
  for (int kt = 0; kt < 4; ++kt) {
    __syncthreads();
    #pragma unroll
    for (int p = 0; p < 4; ++p) {
      int id = t + p*512;
      *(uint4*)((char*)Asm + (id>>2)*80 + (id&3)*16) = *(const uint4*)(Ab[p] + kt*32);
    }
    if (t < 128) {
      float4 f0 = *(const float4*)(wvb + kt*32);
      float4 f1 = *(const float4*)(wvb + kt*32 + 4);
      uint4 bv; bv.x = pk2(f0.x,f0.y); bv.y = pk2(f0.z,f0.w);
      bv.z = pk2(f1.x,f1.y); bv.w = pk2(f1.z,f1.w);
      *(uint4*)((char*)Bsm + (t>>2)*80 + (t&3)*16) = bv;
    }
    __syncthreads();
    bf16x8 am[4], bw[2];
    #pragma unroll
    for (int j = 0; j < 4; ++j) {
      int m = wv8*64 + j*16 + l15;
      am[j] = *(const bf16x8*)((const char*)Asm + m*80 + l4*16);
    }
    #pragma unroll
    for (int i = 0; i < 2; ++i) {
      int o = i*16 + l15;
      bw[i] = *(const bf16x8*)((const char*)Bsm + o*80 + l4*16);
    }
    #pragma unroll
    for (int j = 0; j < 4; ++j)
      #pragma unroll
      for (int i = 0; i < 2; ++i)
        acc[j][i] = __builtin_amdgcn_mfma_f32_16x16x32_bf16(am[j], bw[i], acc[j][i], 0, 0, 0);
  }
  __syncthreads();           // all Asm/Bsm reads done; rp aliases Asm
  #pragma unroll
  for (int i = 0; i < 2; ++i) {
    int o = i*16 + l15;
    float bi = bvp[nh*32 + o];
    #pragma unroll
    for (int j = 0; j < 4; ++j) {
      int m0 = wv8*64 + j*16 + l4*4;
      uint2 pw;
      pw.x = pk2(acc[j][i][0] + bi, acc[j][i][1] + bi);
      pw.y = pk2(acc[j][i][2] + bi, acc[j][i][3] + bi);
      *(uint2*)((char*)rp + o*1040 + m0*2) = pw;
    }
  }
  __syncthreads();
  #pragma unroll
  for (int it = 0; it < 4; ++it) {
    int id = t + it*512;
    int o = id & 31, pp = id >> 5;   // pp 0..63
    unsigned short vv[8];
    #pragma unroll
    for (int oxl = 0; oxl < 8; ++oxl)
      vv[oxl] = *(const unsigned short*)((const char*)rp + o*1040 + (oxl*64 + pp)*2);
    uint4 val;
    val.x = (unsigned)vv[0] | ((unsigned)vv[1]<<16);
    val.y = (unsigned)vv[2] | ((unsigned)vv[3]<<16);
    val.z = (unsigned)vv[4] | ((unsigned)vv[5]<<16);
    val.w = (unsigned)vv[6] | ((unsigned)vv[7]<<16);
    unsigned short* dp = (unsigned short*)vt +
        ((size_t)((b*NHEAD + nh)*DWIN) + pp*32 + o)*NWIN + mt*8;
    *(uint4*)dp = val;
  }
}

// ---------------- shared 128x128 B^T GEMM tile (reg-staged, 2-barrier) ----------------
__device__ __forceinline__ void gemm_tile(const __bf16* __restrict__ A,
                                          const __bf16* __restrict__ B,
                                          const int lda, const int ldb, const int NT,
                                          unsigned short* Asm, unsigned short* Bsm,
                                          f32x4 (&acc)[4][4]) {
  const int t = threadIdx.x;
  const int lane = t & 63, wid = t >> 6;
  const int wm = wid >> 1, wn = wid & 1;
  const int l15 = lane & 15, l4 = lane >> 4;
  const int u0 = t, u1 = t + 256;
  const int ra0 = u0 >> 2, ca0 = u0 & 3;
  const int ra1 = u1 >> 2, ca1 = u1 & 3;
  uint4 ar0 = *(const uint4*)(A + ra0*lda + ca0*8);
  uint4 ar1 = *(const uint4*)(A + ra1*lda + ca1*8);
  uint4 br0 = *(const uint4*)(B + ra0*ldb + ca0*8);
  uint4 br1 = *(const uint4*)(B + ra1*ldb + ca1*8);
  for (int kt = 0; kt < NT; ++kt) {
    __syncthreads();
    *(uint4*)((char*)Asm + ra0*80 + ca0*16) = ar0;
    *(uint4*)((char*)Asm + ra1*80 + ca1*16) = ar1;
    *(uint4*)((char*)Bsm + ra0*80 + ca0*16) = br0;
    *(uint4*)((char*)Bsm + ra1*80 + ca1*16) = br1;
    __syncthreads();
    if (kt + 1 < NT) {
      int k0 = (kt+1)*32;
      ar0 = *(const uint4*)(A + ra0*lda + k0 + ca0*8);
      ar1 = *(const uint4*)(A + ra1*lda + k0 + ca1*8);
      br0 = *(const uint4*)(B + ra0*ldb + k0 + ca0*8);
      br1 = *(const uint4*)(B + ra1*ldb + k0 + ca1*8);
    }
    bf16x8 a[4], bb[4];
    #pragma unroll
    for (int i = 0; i < 4; ++i)
      a[i] = *(const bf16x8*)((const char*)Asm + (wm*64 + i*16 + l15)*80 + l4*16);
    #pragma unroll
    for (int j = 0; j < 4; ++j)
      bb[j] = *(const bf16x8*)((const char*)Bsm + (wn*64 + j*16 + l15)*80 + l4*16);
    #pragma unroll
    for (int i = 0; i < 4; ++i)
      #pragma unroll
      for (int j = 0; j < 4; ++j)
        acc[i][j] = __builtin_amdgcn_mfma_f32_16x16x32_bf16(a[i], bb[j], acc[i][j], 0, 0, 0);
  }
}

// ---------------- scores = qw . kw^T / sqrt(d) ----------------
__global__ __launch_bounds__(256)
void k_scores(const __bf16* __restrict__ qw, const __bf16* __restrict__ kw,
              float* __restrict__ S) {
  __shared__ __align__(16) unsigned short Asm[5120], Bsm[5120];
  const int bnh = blockIdx.y;
  const int mt = blockIdx.x >> 3, nt = blockIdx.x & 7;
  const __bf16* A = qw + (size_t)bnh*NWIN*DWIN + (size_t)mt*128*DWIN;
  const __bf16* B = kw + (size_t)bnh*NWIN*DWIN + (size_t)nt*128*DWIN;
  f32x4 acc[4][4];
  #pragma unroll
  for (int i = 0; i < 4; ++i)
    #pragma unroll
    for (int j = 0; j < 4; ++j) acc[i][j] = fzero();
  gemm_tile(A, B, DWIN, DWIN, 64, Asm, Bsm, acc);
  const float scale = 0.022097086912079608f;  // 1/sqrt(2048)
  const int t = threadIdx.x, lane = t & 63, wid = t >> 6;
  const int wm = wid >> 1, wn = wid & 1, l15 = lane & 15, l4 = lane >> 4;
  float* Sb = S + (size_t)bnh*NWIN*NWIN + (size_t)(mt*128)*NWIN + nt*128;
  #pragma unroll
  for (int i = 0; i < 4; ++i)
    #pragma unroll
    for (int r = 0; r < 4; ++r) {
      int row = wm*64 + i*16 + l4*4 + r;
      #pragma unroll
      for (int j = 0; j < 4; ++j) {
        int col = wn*64 + j*16 + l15;
        Sb[(size_t)row*NWIN + col] = acc[i][j][r] * scale;
      }
    }
}

// ---------------- row softmax: S f32 -> P bf16 ----------------
__global__ __launch_bounds__(256)
void k_softmax(const float* __restrict__ S, __bf16* __restrict__ P) {
  __shared__ float red[8];
  const int row = blockIdx.x;
  const int t = threadIdx.x;
  const float4 v = ((const float4*)(S + (size_t)row*NWIN))[t];
  float m = fmaxf(fmaxf(v.x, v.y), fmaxf(v.z, v.w));
  for (int off = 1; off < 64; off <<= 1) m = fmaxf(m, __shfl_xor(m, off));
  const int wid = t >> 6, lane = t & 63;
  if (lane == 0) red[wid] = m;
  __syncthreads();
  m = fmaxf(fmaxf(red[0], red[1]), fmaxf(red[2], red[3]));
  float e0 = __expf(v.x - m), e1 = __expf(v.y - m), e2 = __expf(v.z - m), e3 = __expf(v.w - m);
  float s = e0 + e1 + e2 + e3;
  for (int off = 1; off < 64; off <<= 1) s += __shfl_xor(s, off);
  if (lane == 0) red[4 + wid] = s;
  __syncthreads();
  s = red[4] + red[5] + red[6] + red[7];
  float inv = 1.0f / s;
  ushort4 o;
  o.x = bf16u(e0*inv); o.y = bf16u(e1*inv); o.z = bf16u(e2*inv); o.w = bf16u(e3*inv);
  ((ushort4*)((unsigned short*)P + (size_t)row*NWIN))[t] = o;
}

// ---------------- y = P . V  (B = vt[d''][m]) -> y3[b][cgrp][h][w][c32] ----------------
__global__ __launch_bounds__(256)
void k_pv(const __bf16* __restrict__ P, const __bf16* __restrict__ vt,
          __bf16* __restrict__ y3) {
  __shared__ __align__(16) unsigned short Asm[5120], Bsm[5120];
  const int bnh = blockIdx.y;
  const int b = bnh >> 2, nh = bnh & 3;
  const int mt = blockIdx.x >> 4, nt = blockIdx.x & 15;
  const __bf16* A = P  + (size_t)bnh*NWIN*NWIN + (size_t)mt*128*NWIN;
  const __bf16* B = vt + (size_t)bnh*DWIN*NWIN + (size_t)nt*128*NWIN;
  f32x4 acc[4][4];
  #pragma unroll
  for (int i = 0; i < 4; ++i)
    #pragma unroll
    for (int j = 0; j < 4; ++j) acc[i][j] = fzero();
  gemm_tile(A, B, NWIN, NWIN, 32, Asm, Bsm, acc);
  const int t = threadIdx.x, lane = t & 63, wid = t >> 6;
  const int wm = wid >> 1, wn = wid & 1, l15 = lane & 15, l4 = lane >> 4;
  unsigned short* yu = (unsigned short*)y3;
  const size_t cbase = (size_t)(b*NHEAD + nh)*65536*32;
  #pragma unroll
  for (int i = 0; i < 4; ++i)
    #pragma unroll
    for (int r = 0; r < 4; ++r) {
      int n = mt*128 + wm*64 + i*16 + l4*4 + r;
      int oyy = n >> 5, oxx = n & 31;
      #pragma unroll
      for (int j = 0; j < 4; ++j) {
        int pp = nt*4 + wn*2 + (j >> 1);
        int dk = (j & 1)*16 + l15;
        int hh = oyy*8 + (pp >> 3), ww = oxx*8 + (pp & 7);
        yu[cbase + ((size_t)hh*256 + ww)*32 + dk] = bf16u(acc[i][j][r]);
      }
    }
}

// ---------------- 3x3 reflect conv + bias + LeakyReLU ----------------
// Half-row blocks; waves split the o-dimension (wave w -> o in [w*32, w*32+32)).
// Weight slices are disjoint per wave -> per-block wot L2 traffic = 288KB exactly.
__global__ __launch_bounds__(256)
void k_conv(const __bf16* __restrict__ y3, const __bf16* __restrict__ wot,
            const float* __restrict__ bo, float* __restrict__ out) {
  __shared__ __align__(16) unsigned short ylds[15840];  // 396 slots * 80B
  const int bid = blockIdx.x;
  const int half = bid & 1, h = (bid >> 1) & 255, b = bid >> 9;
  const int w0 = half * 128;
  const int t = threadIdx.x;
  const int hm1 = (h == 0) ? 1 : h - 1;
  const int hp1 = (h == 255) ? 254 : h + 1;
  const int lane = t & 63, wv = t >> 6;     // wave owns o-range wv*32..wv*32+31
  const int l15 = lane & 15, l4 = lane >> 4;
  f32x4 acc[2][8];
  #pragma unroll
  for (int i = 0; i < 2; ++i)
    #pragma unroll
    for (int j = 0; j < 8; ++j) acc[i][j] = fzero();
  const unsigned short* yu = (const unsigned short*)y3;
  for (int cc = 0; cc < 4; ++cc) {
    const size_t cbase = (size_t)(b*NHEAD + cc)*65536*32;
    __syncthreads();
    #pragma unroll
    for (int it = 0; it < 6; ++it) {
      int u = it*256 + t;
      int seg = u & 3, wl = (u >> 2) & 127, rowr = u >> 9;
      int hh = (rowr == 0) ? hm1 : ((rowr == 1) ? h : hp1);
      int gw = w0 - 1 + wl;
      gw = (gw < 0) ? 1 : ((gw > 255) ? 254 : gw);
      uint4 val = *(const uint4*)(yu + cbase + ((size_t)hh*256 + gw)*32 + seg*8);
      *(uint4*)((char*)ylds + (rowr*132 + wl)*80 + seg*16) = val;
    }
    if (t < 24) {
      int seg = t & 3, wl = 128 + ((t >> 2) & 1), rowr = t >> 3;
      int hh = (rowr == 0) ? hm1 : ((rowr == 1) ? h : hp1);
      int gw = w0 - 1 + wl;
      gw = (gw < 0) ? 1 : ((gw > 255) ? 254 : gw);
      uint4 val = *(const uint4*)(yu + cbase + ((size_t)hh*256 + gw)*32 + seg*8);
      *(uint4*)((char*)ylds + (rowr*132 + wl)*80 + seg*16) = val;
    }
    __syncthreads();
    #pragma unroll
    for (int kk = 0; kk < 9; ++kk) {
      const int ky = kk / 3, kx = kk % 3;
      bf16x8 a[2], bb[8];
      #pragma unroll
      for (int i = 0; i < 2; ++i) {
        int o = wv*32 + i*16 + l15;
        a[i] = *(const bf16x8*)(wot + ((size_t)(kk*4 + cc)*128 + o)*32 + l4*8);
      }
      #pragma unroll
      for (int j = 0; j < 8; ++j) {
        int px = j*16 + l15;
        int R = ky*132 + px + kx;
        bb[j] = *(const bf16x8*)((const char*)ylds + R*80 + l4*16);
      }
      #pragma unroll
      for (int i = 0; i < 2; ++i)
        #pragma unroll
        for (int j = 0; j < 8; ++j)
          acc[i][j] = __builtin_amdgcn_mfma_f32_16x16x32_bf16(a[i], bb[j], acc[i][j], 0, 0, 0);
    }
  }
  #pragma unroll
  for (int i = 0; i < 2; ++i)
    #pragma unroll
    for (int r2 = 0; r2 < 4; ++r2) {
      int o = wv*32 + i*16 + l4*4 + r2;
      float bi = bo[o];
      #pragma unroll
      for (int j = 0; j < 8; ++j) {
        int px = j*16 + l15;
        float v = acc[i][j][r2] + bi;
        v = (v > 0.f) ? v : 0.2f * v;
        out[(size_t)((b*NCH + o)*IMH + h)*IMW + w0 + px] = v;
      }
    }
}

// ---------------- launcher ----------------
extern "C" void kernel_launch(void* const* d_in, const int* in_sizes, int n_in,
                              void* d_out, int out_size, void* d_ws, size_t ws_size,
                              hipStream_t stream) {
  (void)in_sizes; (void)n_in; (void)out_size; (void)ws_size;
  const float* x  = (const float*)d_in[0];
  // d_in[1] = m : mask is a no-op in the reference
  const float* wq = (const float*)d_in[2];
  const float* bq = (const float*)d_in[3];
  const float* wk = (const float*)d_in[4];
  const float* bk = (const float*)d_in[5];
  const float* wv = (const float*)d_in[6];
  const float* bv = (const float*)d_in[7];
  const float* wo = (const float*)d_in[8];
  const float* bo = (const float*)d_in[9];
  float* out = (float*)d_out;
  char* ws = (char*)d_ws;
  // region A [0,64MB): qw -> P ; B [64,128MB): kw -> wot ; C [128,192MB): vt
  // region D [192,256MB): xt16 -> S f32 -> y3 bf16
  __bf16* qw  = (__bf16*)(ws + 0);
  __bf16* kw  = (__bf16*)(ws + 67108864);
  __bf16* vt  = (__bf16*)(ws + 134217728);
  unsigned short* xt16 = (unsigned short*)(ws + 201326592);
  float*  S   = (float*)(ws + 201326592);
  __bf16* P   = (__bf16*)(ws + 0);
  __bf16* y3  = (__bf16*)(ws + 201326592);
  __bf16* wot = (__bf16*)(ws + 67108864);

  k_xpose<<<8192, 256, 0, stream>>>(x, xt16);
  k_qk<<<2048, 512, 0, stream>>>(xt16, wq, wk, bq, bk, qw, kw);
  k_v<<<dim3(512, 4), 512, 0, stream>>>(xt16, wv, bv, vt);
  k_scores<<<dim3(64, 16), 256, 0, stream>>>(qw, kw, S);
  k_prep_wo<<<576, 256, 0, stream>>>(wo, wot);
  k_softmax<<<16384, 256, 0, stream>>>(S, P);
  k_pv<<<dim3(128, 16), 256, 0, stream>>>(P, vt, y3);
  k_conv<<<2048, 256, 0, stream>>>(y3, wot, bo, out);
}